// Round 1
// baseline (587.889 us; speedup 1.0000x reference)
//
#include <hip/hip_runtime.h>

// SpecCnn1d: y[b,o,f] = relu( sum_k x[b, o+k] * w[f,k] ), stride 1
// B=64, L=16384, F=128, K=16, out_len = L-K+1 = 16369
// Output 536 MB fp32 -> HBM write-bound. Conv roofline ~86-95 us; the
// harness's timed region also contains a ~347 us poison-fill (2.1 GB), so
// total dur_us floor is ~433 us.
//
// v2 change vs v1: store float4 instead of float (4 B/lane -> 16 B/lane).
// Each thread owns 4 CONSECUTIVE filters (f-quad) for 8 o-positions, so the
// ReLU'd accumulators for one o are contiguous in y and store as dwordx4.
// x window loads are also float4 (32 B-aligned since o0 and g*8 are
// multiples of 8). v1's dword stores ran the write stream at ~2.7 TB/s
// (43% of the 6.2 TB/s the fill kernel reaches on the same buffer).

constexpr int K_TAPS  = 16;
constexpr int F_FILT  = 128;
constexpr int O_TILE  = 64;    // o positions per block
constexpr int O_PER_T = 8;     // o positions per thread
constexpr int NTHREAD = 256;   // 32 f-quads x 8 o-groups

__global__ __launch_bounds__(NTHREAD) void SpecCnn1d_conv_kernel(
    const float* __restrict__ x,     // [B, L]
    const float* __restrict__ w,     // [F, K]
    float* __restrict__ y,           // [B, out_len, F]
    int L, int out_len)
{
    const int f4 = threadIdx.x & 31;   // filter quad: filters 4*f4 .. 4*f4+3
    const int g  = threadIdx.x >> 5;   // o-group within the block tile
    const int b  = blockIdx.y;
    const int o0 = blockIdx.x * O_TILE;
    const int f  = f4 * 4;

    // 4 filters x 16 taps -> 64 registers, loaded as 16 float4 (coalesced
    // within each 256 B filter row; w is 8 KB, L2-resident after first use).
    float wr[4][K_TAPS];
    #pragma unroll
    for (int ff = 0; ff < 4; ++ff) {
        const float4* w4 = reinterpret_cast<const float4*>(w + (size_t)(f + ff) * K_TAPS);
        #pragma unroll
        for (int i = 0; i < K_TAPS / 4; ++i) {
            float4 v = w4[i];
            wr[ff][4 * i + 0] = v.x;
            wr[ff][4 * i + 1] = v.y;
            wr[ff][4 * i + 2] = v.z;
            wr[ff][4 * i + 3] = v.w;
        }
    }

    const float* xb = x + (size_t)b * L;
    const int    s  = o0 + g * O_PER_T;          // this thread's window start
    float*       yb = y + ((size_t)b * out_len + s) * F_FILT + f;

    float xs[O_PER_T + K_TAPS];                  // 24 floats (need 23)

    if (o0 + O_TILE + K_TAPS <= L) {
        // Fast path (all blocks except blockIdx.x == 255): window fully in
        // bounds AND every o < out_len, so no guards anywhere.
        const float4* xv = reinterpret_cast<const float4*>(xb + s);  // 32 B aligned
        #pragma unroll
        for (int i = 0; i < (O_PER_T + K_TAPS) / 4; ++i) {
            float4 v = xv[i];
            xs[4 * i + 0] = v.x;
            xs[4 * i + 1] = v.y;
            xs[4 * i + 2] = v.z;
            xs[4 * i + 3] = v.w;
        }

        #pragma unroll
        for (int oo = 0; oo < O_PER_T; ++oo) {
            float a0 = 0.0f, a1 = 0.0f, a2 = 0.0f, a3 = 0.0f;
            #pragma unroll
            for (int k = 0; k < K_TAPS; ++k) {
                const float xv_ = xs[oo + k];
                a0 = fmaf(xv_, wr[0][k], a0);
                a1 = fmaf(xv_, wr[1][k], a1);
                a2 = fmaf(xv_, wr[2][k], a2);
                a3 = fmaf(xv_, wr[3][k], a3);
            }
            float4 r;
            r.x = fmaxf(a0, 0.0f);
            r.y = fmaxf(a1, 0.0f);
            r.z = fmaxf(a2, 0.0f);
            r.w = fmaxf(a3, 0.0f);
            *reinterpret_cast<float4*>(yb + (size_t)oo * F_FILT) = r;
        }
    } else {
        // Tail block: clamp reads into bounds (clamped values only feed
        // o >= out_len, which are not stored), guard stores.
        #pragma unroll
        for (int j = 0; j < O_PER_T + K_TAPS; ++j) {
            int xi = s + j;
            xi = (xi < L) ? xi : (L - 1);
            xs[j] = xb[xi];
        }

        #pragma unroll
        for (int oo = 0; oo < O_PER_T; ++oo) {
            float a0 = 0.0f, a1 = 0.0f, a2 = 0.0f, a3 = 0.0f;
            #pragma unroll
            for (int k = 0; k < K_TAPS; ++k) {
                const float xv_ = xs[oo + k];
                a0 = fmaf(xv_, wr[0][k], a0);
                a1 = fmaf(xv_, wr[1][k], a1);
                a2 = fmaf(xv_, wr[2][k], a2);
                a3 = fmaf(xv_, wr[3][k], a3);
            }
            float4 r;
            r.x = fmaxf(a0, 0.0f);
            r.y = fmaxf(a1, 0.0f);
            r.z = fmaxf(a2, 0.0f);
            r.w = fmaxf(a3, 0.0f);
            if (s + oo < out_len)
                *reinterpret_cast<float4*>(yb + (size_t)oo * F_FILT) = r;
        }
    }
}

extern "C" void kernel_launch(void* const* d_in, const int* in_sizes, int n_in,
                              void* d_out, int out_size, void* d_ws, size_t ws_size,
                              hipStream_t stream) {
    const float* x = (const float*)d_in[0];   // 64*16384 fp32
    const float* w = (const float*)d_in[1];   // 128*16  fp32
    float*       y = (float*)d_out;           // 64*16369*128 fp32

    const int B = 64;
    const int L = in_sizes[0] / B;            // 16384
    const int out_len = L - K_TAPS + 1;       // 16369

    dim3 grid((out_len + O_TILE - 1) / O_TILE, B);
    dim3 block(NTHREAD);
    SpecCnn1d_conv_kernel<<<grid, block, 0, stream>>>(x, w, y, L, out_len);
}

// Round 2
// 546.545 us; speedup vs baseline: 1.0756x; 1.0756x over previous
//
#include <hip/hip_runtime.h>

// SpecCnn1d: y[b,o,f] = relu( sum_k x[b, o+k] * w[f,k] ), stride 1
// B=64, L=16384, F=128, K=16, out_len = L-K+1 = 16369
// Output 536 MB fp32 -> HBM write-bound. Conv roofline ~86 us; the timed
// region also contains a ~347 us poison-fill (2.1 GB), so dur_us floor ~433.
//
// v3 (after v2 post-mortem): v2's float4 stores REGRESSED (conv ~196->~241us)
// because it traded away the two things that mattered: wave-uniform scalar
// x loads and 8-waves/SIMD occupancy. v3 keeps x addresses free of threadIdx
// (-> s_load_dwordx4 into SGPRs), gives each lane a filter PAIR
// (f=2*lane, float2 stores: 512B/wave-store, 2x compute per window, VGPR~48),
// and ping-pong double-buffers the x window so the next chunk's scalar loads
// overlap the current chunk's 256 FMAs. Theory: conv is exposed-latency
// bound, not store-width bound.

constexpr int K_TAPS  = 16;
constexpr int F_FILT  = 128;
constexpr int O_TILE  = 64;    // o positions per block (one wave)
constexpr int O_CHUNK = 8;     // o positions per compute burst
constexpr int NTHREAD = 64;    // one wave; lane covers filters 2l, 2l+1
constexpr int XS_N    = O_CHUNK + K_TAPS;  // 24 (need 23; 24 = 6 x float4)

__global__ __launch_bounds__(NTHREAD) void SpecCnn1d_conv_kernel(
    const float* __restrict__ x,     // [B, L]
    const float* __restrict__ w,     // [F, K]
    float* __restrict__ y,           // [B, out_len, F]
    int L, int out_len)
{
    const int lane = threadIdx.x;        // 0..63
    const int f    = lane << 1;          // filter pair 2l, 2l+1
    const int b    = blockIdx.y;
    const int o0   = blockIdx.x * O_TILE;

    // Weight pair -> 32 VGPRs. Lane reads 128 contiguous bytes at f*64:
    // wave covers the whole 8 KB w, fully coalesced, L2-hot after block 0.
    float w0[K_TAPS], w1[K_TAPS];
    {
        const float4* wp = reinterpret_cast<const float4*>(w + (size_t)f * K_TAPS);
        #pragma unroll
        for (int i = 0; i < K_TAPS / 4; ++i) {
            float4 v0 = wp[i];          // row f
            float4 v1 = wp[i + 4];      // row f+1
            w0[4*i+0] = v0.x; w0[4*i+1] = v0.y; w0[4*i+2] = v0.z; w0[4*i+3] = v0.w;
            w1[4*i+0] = v1.x; w1[4*i+1] = v1.y; w1[4*i+2] = v1.z; w1[4*i+3] = v1.w;
        }
    }

    const float* xb = x + (size_t)b * L;
    // float2 view: row stride between o's is F_FILT/2 = 64 float2.
    float2* yb = reinterpret_cast<float2*>(y + ((size_t)b * out_len + o0) * F_FILT) + lane;

    // Fast path: every read (up to o0+79) and every store (o < o0+64) in
    // bounds. True for all blockIdx.x <= 254; only the last block tails.
    if (o0 + O_TILE + K_TAPS <= L) {
        float xs0[XS_N], xs1[XS_N];

        // Wave-uniform window load: address has NO threadIdx dependence ->
        // compiler emits s_load_dwordx4 (SGPRs, SMEM pipe, no VMEM).
        auto LOADU = [&](float* xs, int oc) {
            const float4* xp = reinterpret_cast<const float4*>(xb + o0 + oc);
            #pragma unroll
            for (int i = 0; i < XS_N / 4; ++i) {
                float4 v = xp[i];
                xs[4*i+0] = v.x; xs[4*i+1] = v.y; xs[4*i+2] = v.z; xs[4*i+3] = v.w;
            }
        };
        // 8 outputs: 256 FMAs (2 filters x 16 taps x 8 o) + 8 float2 stores.
        auto COMP = [&](const float* xs, int oc) {
            #pragma unroll
            for (int oo = 0; oo < O_CHUNK; ++oo) {
                float a0 = 0.0f, a1 = 0.0f;
                #pragma unroll
                for (int k = 0; k < K_TAPS; ++k) {
                    const float xv = xs[oo + k];   // SGPR operand
                    a0 = fmaf(xv, w0[k], a0);
                    a1 = fmaf(xv, w1[k], a1);
                }
                float2 r;
                r.x = fmaxf(a0, 0.0f);
                r.y = fmaxf(a1, 0.0f);
                yb[(size_t)(oc + oo) * (F_FILT / 2)] = r;
            }
        };

        LOADU(xs0, 0);
        #pragma unroll
        for (int oc = 0; oc < O_TILE; oc += 2 * O_CHUNK) {
            LOADU(xs1, oc + O_CHUNK);        // prefetch next window
            COMP(xs0, oc);                   // compute under the loads
            if (oc + 2 * O_CHUNK < O_TILE)
                LOADU(xs0, oc + 2 * O_CHUNK);
            COMP(xs1, oc + O_CHUNK);
        }
    } else {
        // Tail block (blockIdx.x == 255): clamp reads (clamped values only
        // feed o >= out_len, never stored), guard stores.
        for (int oc = 0; oc < O_TILE; oc += O_CHUNK) {
            const int base = o0 + oc;
            float xs[XS_N];
            #pragma unroll
            for (int j = 0; j < XS_N; ++j) {
                int xi = base + j;
                xi = (xi < L) ? xi : (L - 1);
                xs[j] = xb[xi];
            }
            #pragma unroll
            for (int oo = 0; oo < O_CHUNK; ++oo) {
                float a0 = 0.0f, a1 = 0.0f;
                #pragma unroll
                for (int k = 0; k < K_TAPS; ++k) {
                    const float xv = xs[oo + k];
                    a0 = fmaf(xv, w0[k], a0);
                    a1 = fmaf(xv, w1[k], a1);
                }
                float2 r;
                r.x = fmaxf(a0, 0.0f);
                r.y = fmaxf(a1, 0.0f);
                if (base + oo < out_len)
                    yb[(size_t)(oc + oo) * (F_FILT / 2)] = r;
            }
        }
    }
}

extern "C" void kernel_launch(void* const* d_in, const int* in_sizes, int n_in,
                              void* d_out, int out_size, void* d_ws, size_t ws_size,
                              hipStream_t stream) {
    const float* x = (const float*)d_in[0];   // 64*16384 fp32
    const float* w = (const float*)d_in[1];   // 128*16  fp32
    float*       y = (float*)d_out;           // 64*16369*128 fp32

    const int B = 64;
    const int L = in_sizes[0] / B;            // 16384
    const int out_len = L - K_TAPS + 1;       // 16369

    dim3 grid((out_len + O_TILE - 1) / O_TILE, B);
    dim3 block(NTHREAD);
    SpecCnn1d_conv_kernel<<<grid, block, 0, stream>>>(x, w, y, L, out_len);
}